// Round 5
// baseline (1059.536 us; speedup 1.0000x reference)
//
#include <hip/hip_runtime.h>
#include <hip/hip_bf16.h>
#include <math.h>

// Problem constants
#define DDIM   300
#define PFN    12
#define LFN    8
#define ICH    21      // PF + LF + 1
#define TPB    64      // ONE wave per block; 4 lanes per sample
#define SPB    16      // samples per block
#define SLOT_DW 99     // per-sample feature slot: 9 positions * 11 dwords

__device__ __forceinline__ float lrelu(float v) { return v > 0.0f ? v : 0.2f * v; }

__device__ __forceinline__ unsigned int pack2(float a, float b) {
    union { __hip_bfloat162 h; unsigned int u; } cv;
    cv.h.x = __float2bfloat16(a);
    cv.h.y = __float2bfloat16(b);
    return cv.u;
}
__device__ __forceinline__ float bflo(unsigned int u) {
    union { unsigned int i; float f; } c; c.i = u << 16; return c.f;
}
__device__ __forceinline__ float bfhi(unsigned int u) {
    union { unsigned int i; float f; } c; c.i = u & 0xffff0000u; return c.f;
}

// 3x3 conv (pad=1) on a 3x3 grid: accumulate one input channel into 9 outputs.
__device__ __forceinline__ void conv_acc(float o[9], const float* __restrict__ w, const float fv[9]) {
#pragma unroll
    for (int t = 0; t < 9; ++t) {
        const int ky = t / 3 - 1, kx = t % 3 - 1;
        const float wv = w[t];
#pragma unroll
        for (int y = 0; y < 3; ++y) {
            const int iy = y + ky;
            if (iy < 0 || iy > 2) continue;
#pragma unroll
            for (int x = 0; x < 3; ++x) {
                const int ix = x + kx;
                if (ix < 0 || ix > 2) continue;
                o[y * 3 + x] = fmaf(wv, fv[iy * 3 + ix], o[y * 3 + x]);
            }
        }
    }
}

// Session evidence: the 2nd launch_bounds arg acts as the waves-per-EU CAP.
// (64,1) pinned residency to 1 wave/SIMD (occupancy 11.5% with a 4x grid) —
// every memory stall fully exposed. (64,4) allows 4 waves/EU (16 waves/CU)
// with RA budget 512/4 = 128 VGPRs; fc2 unroll reduced 4->2 so the peak
// live-set fits 128 without re-triggering the spill storm of rounds 1-3.
__launch_bounds__(TPB, 4)
__global__ void disc_kernel(
    const int* __restrict__ state, const int* __restrict__ des,
    const int* __restrict__ act,
    const int* __restrict__ asp_g,   // action_state_pad (S,9)
    const int* __restrict__ pmp_g,   // policy_mask_pad  (S,9)
    const float* __restrict__ path_feature,  // (S,D,12)
    const float* __restrict__ link_feature,  // (S,8)
    const float* __restrict__ w1, const float* __restrict__ b1,   // conv1 (20,21,3,3)
    const float* __restrict__ w2, const float* __restrict__ b2,   // conv2 (30,20,2,2)
    const float* __restrict__ fw1, const float* __restrict__ fb1, // (120,38)
    const float* __restrict__ fw2, const float* __restrict__ fb2, // (84,120)
    const float* __restrict__ fw3, const float* __restrict__ fb3, // (1,84)
    float* __restrict__ out, int n)
{
    __shared__ unsigned int feat[SPB * SLOT_DW];  // 6336 B

    const int tid    = threadIdx.x;
    const int lane4  = tid & 3;       // lane within sample quad
    const int lsamp  = tid >> 2;      // sample within block
    const int sample = blockIdx.x * SPB + lsamp;
    if (sample >= n) return;

    const int s  = state[sample];
    const int d  = des[sample];
    const int ai = act[sample];

    const int* asp = asp_g + s * 9;
    const int* pmp = pmp_g + s * 9;
    unsigned int* fslot = feat + lsamp * SLOT_DW;

    // ---- Cooperative gather: lane k handles positions k, k+4, k+8.
    // NEW_INDEX packed as nibbles: p -> {7,0,1,6,8,2,5,4,3}
#pragma unroll
    for (int t = 0; t < 3; ++t) {
        const int p = lane4 + 4 * t;
        if (p < 9) {
            const int a  = (int)((0x345286107ULL >> (4 * p)) & 0xF);
            const int na = asp[a];
            const float m = (float)pmp[a];
            const float4* pf = (const float4*)(path_feature + (na * DDIM + d) * PFN);
            const float4 v0 = pf[0], v1 = pf[1], v2 = pf[2];
            const float4* lf = (const float4*)(link_feature + na * LFN);
            const float4 u0 = lf[0], u1 = lf[1];
            unsigned int* dst = fslot + p * 11;   // 22 bf16 per position (dword aligned)
            dst[0] = pack2(v0.x, v0.y); dst[1] = pack2(v0.z, v0.w);
            dst[2] = pack2(v1.x, v1.y); dst[3] = pack2(v1.z, v1.w);
            dst[4] = pack2(v2.x, v2.y); dst[5] = pack2(v2.z, v2.w);
            dst[6] = pack2(u0.x, u0.y); dst[7] = pack2(u0.z, u0.w);
            dst[8] = pack2(u1.x, u1.y); dst[9] = pack2(u1.z, u1.w);
            dst[10] = pack2(m, 0.0f);             // channel 20 = mask, high half = pad
        }
    }
    // One wave per block: quad lanes share the wave, so ordering our own
    // ds_writes before cross-lane ds_reads only needs lgkmcnt drain.
    asm volatile("s_waitcnt lgkmcnt(0)" ::: "memory");

    // ---- conv1: lane k computes output channels [5k, 5k+5)
    // Weights from global: w1 is 15 KB -> L1-resident, no LDS staging needed.
    const int oc0 = lane4 * 5;
    float o[5][9];
#pragma unroll
    for (int c = 0; c < 5; ++c) {
        const float bb = b1[oc0 + c];
#pragma unroll
        for (int q = 0; q < 9; ++q) o[c][q] = bb;
    }

#pragma unroll 1
    for (int icp = 0; icp < 10; ++icp) {          // ic pairs 0..19
        unsigned int fw[9];
#pragma unroll
        for (int q = 0; q < 9; ++q) fw[q] = fslot[q * 11 + icp];
        float flo[9], fhi[9];
#pragma unroll
        for (int q = 0; q < 9; ++q) { flo[q] = bflo(fw[q]); fhi[q] = bfhi(fw[q]); }
#pragma unroll
        for (int c = 0; c < 5; ++c) {
            const float* wl = w1 + ((oc0 + c) * ICH + 2 * icp) * 9;
            conv_acc(o[c], wl,     flo);
            conv_acc(o[c], wl + 9, fhi);
        }
    }
    {   // ic = 20 (mask channel)
        float f20[9];
#pragma unroll
        for (int q = 0; q < 9; ++q) f20[q] = bflo(fslot[q * 11 + 10]);
#pragma unroll
        for (int c = 0; c < 5; ++c)
            conv_acc(o[c], w1 + ((oc0 + c) * ICH + 20) * 9, f20);
    }

    // ---- lrelu + 2x2 maxpool (stride 1) on local 5 channels
    float pooled[5][4];
#pragma unroll
    for (int c = 0; c < 5; ++c) {
        float v[9];
#pragma unroll
        for (int q = 0; q < 9; ++q) v[q] = lrelu(o[c][q]);
        pooled[c][0] = fmaxf(fmaxf(v[0], v[1]), fmaxf(v[3], v[4]));
        pooled[c][1] = fmaxf(fmaxf(v[1], v[2]), fmaxf(v[4], v[5]));
        pooled[c][2] = fmaxf(fmaxf(v[3], v[4]), fmaxf(v[6], v[7]));
        pooled[c][3] = fmaxf(fmaxf(v[4], v[5]), fmaxf(v[7], v[8]));
    }

    // ---- conv2 (2x2 VALID): per-lane partial over its 5 oc, quad butterfly reduce.
    float x30[30];
#pragma unroll
    for (int j = 0; j < 30; ++j) {
        const float4* wr = (const float4*)(w2 + j * 80 + oc0 * 4);  // 16B aligned
        float acc = 0.0f;
#pragma unroll
        for (int c = 0; c < 5; ++c) {
            const float4 wv = wr[c];
            acc = fmaf(wv.x, pooled[c][0], acc);
            acc = fmaf(wv.y, pooled[c][1], acc);
            acc = fmaf(wv.z, pooled[c][2], acc);
            acc = fmaf(wv.w, pooled[c][3], acc);
        }
        acc += __shfl_xor(acc, 1, 64);
        acc += __shfl_xor(acc, 2, 64);
        x30[j] = lrelu(acc + b2[j]);
    }

    // ---- fc1 (38->120): lane k computes rows [30k, 30k+30)
    float h1[30];
    const int j0 = lane4 * 30;
#pragma unroll
    for (int jj = 0; jj < 30; ++jj) {
        const float* wr = fw1 + (j0 + jj) * 38;
        float acc = fb1[j0 + jj] + wr[30 + ai];   // one-hot(act) contribution
        const float2* wp = (const float2*)wr;     // 8B aligned (38*4 = 152)
#pragma unroll
        for (int m = 0; m < 15; ++m) {
            const float2 wv = wp[m];
            acc = fmaf(wv.x, x30[2 * m],     acc);
            acc = fmaf(wv.y, x30[2 * m + 1], acc);
        }
        h1[jj] = lrelu(acc);
    }

    // ---- fc2 (120->84) + fc3 (84->1): per-lane partial dot over its 30 h1,
    // butterfly reduce per output, fold straight into fc3 (no h2 array).
    // unroll 2 (was 4): halves in-flight weight regs so peak live-set fits
    // the 128-VGPR budget of launch_bounds(64,4). h1 reads stay static.
    float z = fb3[0];
#pragma unroll 2
    for (int i = 0; i < 84; ++i) {
        const float2* wp = (const float2*)(fw2 + i * 120 + j0);  // 8B aligned
        float a = 0.0f;
#pragma unroll
        for (int m = 0; m < 15; ++m) {
            const float2 wv = wp[m];
            a = fmaf(wv.x, h1[2 * m],     a);
            a = fmaf(wv.y, h1[2 * m + 1], a);
        }
        a += __shfl_xor(a, 1, 64);
        a += __shfl_xor(a, 2, 64);
        z = fmaf(fw3[i], lrelu(a + fb2[i]), z);
    }

    if (lane4 == 0)
        out[sample] = 1.0f / (1.0f + __expf(-z));
}

extern "C" void kernel_launch(void* const* d_in, const int* in_sizes, int n_in,
                              void* d_out, int out_size, void* d_ws, size_t ws_size,
                              hipStream_t stream) {
    const int*   state = (const int*)d_in[0];
    const int*   des   = (const int*)d_in[1];
    const int*   act   = (const int*)d_in[2];
    const int*   asp   = (const int*)d_in[3];
    const int*   pmp   = (const int*)d_in[4];
    const float* pathf = (const float*)d_in[5];
    const float* linkf = (const float*)d_in[6];
    const float* w1    = (const float*)d_in[7];
    const float* b1    = (const float*)d_in[8];
    const float* w2    = (const float*)d_in[9];
    const float* b2    = (const float*)d_in[10];
    const float* fw1   = (const float*)d_in[11];
    const float* fb1   = (const float*)d_in[12];
    const float* fw2   = (const float*)d_in[13];
    const float* fb2   = (const float*)d_in[14];
    const float* fw3   = (const float*)d_in[15];
    const float* fb3   = (const float*)d_in[16];

    const int n = in_sizes[0];
    dim3 grid((n + SPB - 1) / SPB), block(TPB);
    hipLaunchKernelGGL(disc_kernel, grid, block, 0, stream,
                       state, des, act, asp, pmp, pathf, linkf,
                       w1, b1, w2, b2, fw1, fb1, fw2, fb2, fw3, fb3,
                       (float*)d_out, n);
}

// Round 6
// 687.921 us; speedup vs baseline: 1.5402x; 1.5402x over previous
//
#include <hip/hip_runtime.h>
#include <hip/hip_bf16.h>
#include <math.h>

// Problem constants
#define DDIM   300
#define PFN    12
#define LFN    8
#define ICH    21      // PF + LF + 1
#define TPB    64      // ONE wave per block; 4 lanes per sample
#define SPB    16      // samples per block
#define SLOT_DW 99     // per-sample feature slot: 9 positions * 11 dwords

__device__ __forceinline__ float lrelu(float v) { return v > 0.0f ? v : 0.2f * v; }

__device__ __forceinline__ unsigned int pack2(float a, float b) {
    union { __hip_bfloat162 h; unsigned int u; } cv;
    cv.h.x = __float2bfloat16(a);
    cv.h.y = __float2bfloat16(b);
    return cv.u;
}
__device__ __forceinline__ float bflo(unsigned int u) {
    union { unsigned int i; float f; } c; c.i = u << 16; return c.f;
}
__device__ __forceinline__ float bfhi(unsigned int u) {
    union { unsigned int i; float f; } c; c.i = u & 0xffff0000u; return c.f;
}

// 3x3 conv (pad=1) on a 3x3 grid: accumulate one input channel into 9 outputs.
__device__ __forceinline__ void conv_acc(float o[9], const float* __restrict__ w, const float fv[9]) {
#pragma unroll
    for (int t = 0; t < 9; ++t) {
        const int ky = t / 3 - 1, kx = t % 3 - 1;
        const float wv = w[t];
#pragma unroll
        for (int y = 0; y < 3; ++y) {
            const int iy = y + ky;
            if (iy < 0 || iy > 2) continue;
#pragma unroll
            for (int x = 0; x < 3; ++x) {
                const int ix = x + kx;
                if (ix < 0 || ix > 2) continue;
                o[y * 3 + x] = fmaf(wv, fv[iy * 3 + ix], o[y * 3 + x]);
            }
        }
    }
}

// Session-derived toolchain model (6 configs): effective VGPR budget = 256/W
// where W is the 2nd launch_bounds arg, and W also caps resident waves/EU.
//   (64,1): 132 VGPR clean, but 1 wave/EU resident (occ 11.5%)  -> latency-bound
//   (*,4):  64 VGPR, spill storm (0.7-1.5 GB/dispatch scratch)  -> HBM-bound
// (64,2) is the untried sweet spot: budget 128 (fits our ~95-reg live set
// after trimming conv1 temps), residency 2 waves/EU.
__launch_bounds__(TPB, 2)
__global__ void disc_kernel(
    const int* __restrict__ state, const int* __restrict__ des,
    const int* __restrict__ act,
    const int* __restrict__ asp_g,   // action_state_pad (S,9)
    const int* __restrict__ pmp_g,   // policy_mask_pad  (S,9)
    const float* __restrict__ path_feature,  // (S,D,12)
    const float* __restrict__ link_feature,  // (S,8)
    const float* __restrict__ w1, const float* __restrict__ b1,   // conv1 (20,21,3,3)
    const float* __restrict__ w2, const float* __restrict__ b2,   // conv2 (30,20,2,2)
    const float* __restrict__ fw1, const float* __restrict__ fb1, // (120,38)
    const float* __restrict__ fw2, const float* __restrict__ fb2, // (84,120)
    const float* __restrict__ fw3, const float* __restrict__ fb3, // (1,84)
    float* __restrict__ out, int n)
{
    __shared__ unsigned int feat[SPB * SLOT_DW];  // 6336 B

    const int tid    = threadIdx.x;
    const int lane4  = tid & 3;       // lane within sample quad
    const int lsamp  = tid >> 2;      // sample within block
    const int sample = blockIdx.x * SPB + lsamp;
    if (sample >= n) return;

    const int s  = state[sample];
    const int d  = des[sample];
    const int ai = act[sample];

    const int* asp = asp_g + s * 9;
    const int* pmp = pmp_g + s * 9;
    unsigned int* fslot = feat + lsamp * SLOT_DW;

    // ---- Cooperative gather: lane k handles positions k, k+4, k+8.
    // NEW_INDEX packed as nibbles: p -> {7,0,1,6,8,2,5,4,3}
#pragma unroll
    for (int t = 0; t < 3; ++t) {
        const int p = lane4 + 4 * t;
        if (p < 9) {
            const int a  = (int)((0x345286107ULL >> (4 * p)) & 0xF);
            const int na = asp[a];
            const float m = (float)pmp[a];
            const float4* pf = (const float4*)(path_feature + (na * DDIM + d) * PFN);
            const float4 v0 = pf[0], v1 = pf[1], v2 = pf[2];
            const float4* lf = (const float4*)(link_feature + na * LFN);
            const float4 u0 = lf[0], u1 = lf[1];
            unsigned int* dst = fslot + p * 11;   // 22 bf16 per position (dword aligned)
            dst[0] = pack2(v0.x, v0.y); dst[1] = pack2(v0.z, v0.w);
            dst[2] = pack2(v1.x, v1.y); dst[3] = pack2(v1.z, v1.w);
            dst[4] = pack2(v2.x, v2.y); dst[5] = pack2(v2.z, v2.w);
            dst[6] = pack2(u0.x, u0.y); dst[7] = pack2(u0.z, u0.w);
            dst[8] = pack2(u1.x, u1.y); dst[9] = pack2(u1.z, u1.w);
            dst[10] = pack2(m, 0.0f);             // channel 20 = mask, high half = pad
        }
    }
    // One wave per block: quad lanes share the wave, so ordering our own
    // ds_writes before cross-lane ds_reads only needs lgkmcnt drain.
    asm volatile("s_waitcnt lgkmcnt(0)" ::: "memory");

    // ---- conv1: lane k computes output channels [5k, 5k+5)
    // Weights from global: w1 is 15 KB -> L1-resident, no LDS staging needed.
    const int oc0 = lane4 * 5;
    float o[5][9];
#pragma unroll
    for (int c = 0; c < 5; ++c) {
        const float bb = b1[oc0 + c];
#pragma unroll
        for (int q = 0; q < 9; ++q) o[c][q] = bb;
    }

    // lo/hi halves processed SEQUENTIALLY through one fv[9] buffer (not
    // flo[9]+fhi[9] in parallel): -9 live VGPRs so the 128 budget holds.
#pragma unroll 1
    for (int icp = 0; icp < 10; ++icp) {          // ic pairs 0..19
        unsigned int fw[9];
#pragma unroll
        for (int q = 0; q < 9; ++q) fw[q] = fslot[q * 11 + icp];
        float fv[9];
#pragma unroll
        for (int q = 0; q < 9; ++q) fv[q] = bflo(fw[q]);
#pragma unroll
        for (int c = 0; c < 5; ++c)
            conv_acc(o[c], w1 + ((oc0 + c) * ICH + 2 * icp) * 9, fv);
#pragma unroll
        for (int q = 0; q < 9; ++q) fv[q] = bfhi(fw[q]);
#pragma unroll
        for (int c = 0; c < 5; ++c)
            conv_acc(o[c], w1 + ((oc0 + c) * ICH + 2 * icp + 1) * 9, fv);
    }
    {   // ic = 20 (mask channel)
        float f20[9];
#pragma unroll
        for (int q = 0; q < 9; ++q) f20[q] = bflo(fslot[q * 11 + 10]);
#pragma unroll
        for (int c = 0; c < 5; ++c)
            conv_acc(o[c], w1 + ((oc0 + c) * ICH + 20) * 9, f20);
    }

    // ---- lrelu + 2x2 maxpool (stride 1) on local 5 channels
    float pooled[5][4];
#pragma unroll
    for (int c = 0; c < 5; ++c) {
        float v[9];
#pragma unroll
        for (int q = 0; q < 9; ++q) v[q] = lrelu(o[c][q]);
        pooled[c][0] = fmaxf(fmaxf(v[0], v[1]), fmaxf(v[3], v[4]));
        pooled[c][1] = fmaxf(fmaxf(v[1], v[2]), fmaxf(v[4], v[5]));
        pooled[c][2] = fmaxf(fmaxf(v[3], v[4]), fmaxf(v[6], v[7]));
        pooled[c][3] = fmaxf(fmaxf(v[4], v[5]), fmaxf(v[7], v[8]));
    }

    // ---- conv2 (2x2 VALID): per-lane partial over its 5 oc, quad butterfly reduce.
    // FULLY unrolled: x30[j] writes must be statically indexed (rule #20).
    float x30[30];
#pragma unroll
    for (int j = 0; j < 30; ++j) {
        const float4* wr = (const float4*)(w2 + j * 80 + oc0 * 4);  // 16B aligned
        float acc = 0.0f;
#pragma unroll
        for (int c = 0; c < 5; ++c) {
            const float4 wv = wr[c];
            acc = fmaf(wv.x, pooled[c][0], acc);
            acc = fmaf(wv.y, pooled[c][1], acc);
            acc = fmaf(wv.z, pooled[c][2], acc);
            acc = fmaf(wv.w, pooled[c][3], acc);
        }
        acc += __shfl_xor(acc, 1, 64);
        acc += __shfl_xor(acc, 2, 64);
        x30[j] = lrelu(acc + b2[j]);
    }

    // ---- fc1 (38->120): lane k computes rows [30k, 30k+30)
    // FULLY unrolled: h1[jj] writes must be statically indexed (rule #20).
    float h1[30];
    const int j0 = lane4 * 30;
#pragma unroll
    for (int jj = 0; jj < 30; ++jj) {
        const float* wr = fw1 + (j0 + jj) * 38;
        float acc = fb1[j0 + jj] + wr[30 + ai];   // one-hot(act) contribution
        const float2* wp = (const float2*)wr;     // 8B aligned (38*4 = 152)
#pragma unroll
        for (int m = 0; m < 15; ++m) {
            const float2 wv = wp[m];
            acc = fmaf(wv.x, x30[2 * m],     acc);
            acc = fmaf(wv.y, x30[2 * m + 1], acc);
        }
        h1[jj] = lrelu(acc);
    }

    // ---- fc2 (120->84) + fc3 (84->1): per-lane partial dot over its 30 h1,
    // butterfly reduce per output, fold straight into fc3 (no h2 array).
    float z = fb3[0];
#pragma unroll 2
    for (int i = 0; i < 84; ++i) {
        const float2* wp = (const float2*)(fw2 + i * 120 + j0);  // 8B aligned
        float a = 0.0f;
#pragma unroll
        for (int m = 0; m < 15; ++m) {
            const float2 wv = wp[m];
            a = fmaf(wv.x, h1[2 * m],     a);
            a = fmaf(wv.y, h1[2 * m + 1], a);
        }
        a += __shfl_xor(a, 1, 64);
        a += __shfl_xor(a, 2, 64);
        z = fmaf(fw3[i], lrelu(a + fb2[i]), z);
    }

    if (lane4 == 0)
        out[sample] = 1.0f / (1.0f + __expf(-z));
}

extern "C" void kernel_launch(void* const* d_in, const int* in_sizes, int n_in,
                              void* d_out, int out_size, void* d_ws, size_t ws_size,
                              hipStream_t stream) {
    const int*   state = (const int*)d_in[0];
    const int*   des   = (const int*)d_in[1];
    const int*   act   = (const int*)d_in[2];
    const int*   asp   = (const int*)d_in[3];
    const int*   pmp   = (const int*)d_in[4];
    const float* pathf = (const float*)d_in[5];
    const float* linkf = (const float*)d_in[6];
    const float* w1    = (const float*)d_in[7];
    const float* b1    = (const float*)d_in[8];
    const float* w2    = (const float*)d_in[9];
    const float* b2    = (const float*)d_in[10];
    const float* fw1   = (const float*)d_in[11];
    const float* fb1   = (const float*)d_in[12];
    const float* fw2   = (const float*)d_in[13];
    const float* fb2   = (const float*)d_in[14];
    const float* fw3   = (const float*)d_in[15];
    const float* fb3   = (const float*)d_in[16];

    const int n = in_sizes[0];
    dim3 grid((n + SPB - 1) / SPB), block(TPB);
    hipLaunchKernelGGL(disc_kernel, grid, block, 0, stream,
                       state, des, act, asp, pmp, pathf, linkf,
                       w1, b1, w2, b2, fw1, fb1, fw2, fb2, fw3, fb3,
                       (float*)d_out, n);
}

// Round 7
// 548.040 us; speedup vs baseline: 1.9333x; 1.2552x over previous
//
#include <hip/hip_runtime.h>
#include <hip/hip_bf16.h>
#include <math.h>

// Problem constants
#define DDIM   300
#define PFN    12
#define LFN    8
#define ICH    21      // PF + LF + 1
#define TPB    256     // 4 waves/block; 4 lanes per sample
#define SPB    64      // samples per block
#define SLOT_DW 99     // per-sample feature slot: 9 positions * 11 dwords
#define W1N    3780    // 20*21*9  conv1 weights (15.1 KB)
#define FW2N   10080   // 84*120   fc2 weights   (40.3 KB)

__device__ __forceinline__ float lrelu(float v) { return v > 0.0f ? v : 0.2f * v; }

__device__ __forceinline__ unsigned int pack2(float a, float b) {
    union { __hip_bfloat162 h; unsigned int u; } cv;
    cv.h.x = __float2bfloat16(a);
    cv.h.y = __float2bfloat16(b);
    return cv.u;
}
__device__ __forceinline__ float bflo(unsigned int u) {
    union { unsigned int i; float f; } c; c.i = u << 16; return c.f;
}
__device__ __forceinline__ float bfhi(unsigned int u) {
    union { unsigned int i; float f; } c; c.i = u & 0xffff0000u; return c.f;
}

// 3x3 conv (pad=1) on a 3x3 grid: accumulate one input channel into 9 outputs.
__device__ __forceinline__ void conv_acc(float o[9], const float* __restrict__ w, const float fv[9]) {
#pragma unroll
    for (int t = 0; t < 9; ++t) {
        const int ky = t / 3 - 1, kx = t % 3 - 1;
        const float wv = w[t];
#pragma unroll
        for (int y = 0; y < 3; ++y) {
            const int iy = y + ky;
            if (iy < 0 || iy > 2) continue;
#pragma unroll
            for (int x = 0; x < 3; ++x) {
                const int ix = x + kx;
                if (ix < 0 || ix > 2) continue;
                o[y * 3 + x] = fmaf(wv, fv[iy * 3 + ix], o[y * 3 + x]);
            }
        }
    }
}

// Session toolchain model: effective VGPR budget = 256/W (W = 2nd arg), which
// also sets resident waves/EU. r6 proved (.,2)->128 VGPR clean + 2 waves/EU,
// but dur didn't move vs 1 wave/EU at constant VALUBusy ~24% => per-CU VECTOR
// MEMORY pipe saturated (~2800 VMEM/wave from per-lane weight loads).
// This round: w1 + fw2 (the two biggest VMEM consumers, 2205 instrs/wave)
// move to LDS (fp32, no precision change). LDS = 80.8 KB -> still 2 blocks/CU
// = 2 waves/EU (residency held constant; only the pipe assignment changes).
__launch_bounds__(TPB, 2)
__global__ void disc_kernel(
    const int* __restrict__ state, const int* __restrict__ des,
    const int* __restrict__ act,
    const int* __restrict__ asp_g,   // action_state_pad (S,9)
    const int* __restrict__ pmp_g,   // policy_mask_pad  (S,9)
    const float* __restrict__ path_feature,  // (S,D,12)
    const float* __restrict__ link_feature,  // (S,8)
    const float* __restrict__ w1, const float* __restrict__ b1,   // conv1 (20,21,3,3)
    const float* __restrict__ w2, const float* __restrict__ b2,   // conv2 (30,20,2,2)
    const float* __restrict__ fw1, const float* __restrict__ fb1, // (120,38)
    const float* __restrict__ fw2, const float* __restrict__ fb2, // (84,120)
    const float* __restrict__ fw3, const float* __restrict__ fb3, // (1,84)
    float* __restrict__ out, int n)
{
    __shared__ __align__(16) float w1s[W1N];      // 15120 B
    __shared__ __align__(16) float fw2s[FW2N];    // 40320 B
    __shared__ unsigned int feat[SPB * SLOT_DW];  // 25344 B  -> total 80784 B

    const int tid = threadIdx.x;

    // ---- Stage conv1 + fc2 weights to LDS once per block (float4, coalesced).
    {
        const float4* s1 = (const float4*)w1;   float4* d1 = (float4*)w1s;
        for (int i = tid; i < W1N / 4; i += TPB) d1[i] = s1[i];
        const float4* s2 = (const float4*)fw2;  float4* d2 = (float4*)fw2s;
        for (int i = tid; i < FW2N / 4; i += TPB) d2[i] = s2[i];
    }
    __syncthreads();

    const int lane4  = tid & 3;       // lane within sample quad
    const int lsamp  = tid >> 2;      // sample within block
    const int sample = blockIdx.x * SPB + lsamp;
    if (sample >= n) return;

    const int s  = state[sample];
    const int d  = des[sample];
    const int ai = act[sample];

    const int* asp = asp_g + s * 9;
    const int* pmp = pmp_g + s * 9;
    unsigned int* fslot = feat + lsamp * SLOT_DW;

    // ---- Cooperative gather: lane k handles positions k, k+4, k+8.
    // NEW_INDEX packed as nibbles: p -> {7,0,1,6,8,2,5,4,3}
#pragma unroll
    for (int t = 0; t < 3; ++t) {
        const int p = lane4 + 4 * t;
        if (p < 9) {
            const int a  = (int)((0x345286107ULL >> (4 * p)) & 0xF);
            const int na = asp[a];
            const float m = (float)pmp[a];
            const float4* pf = (const float4*)(path_feature + (na * DDIM + d) * PFN);
            const float4 v0 = pf[0], v1 = pf[1], v2 = pf[2];
            const float4* lf = (const float4*)(link_feature + na * LFN);
            const float4 u0 = lf[0], u1 = lf[1];
            unsigned int* dst = fslot + p * 11;   // 22 bf16 per position (dword aligned)
            dst[0] = pack2(v0.x, v0.y); dst[1] = pack2(v0.z, v0.w);
            dst[2] = pack2(v1.x, v1.y); dst[3] = pack2(v1.z, v1.w);
            dst[4] = pack2(v2.x, v2.y); dst[5] = pack2(v2.z, v2.w);
            dst[6] = pack2(u0.x, u0.y); dst[7] = pack2(u0.z, u0.w);
            dst[8] = pack2(u1.x, u1.y); dst[9] = pack2(u1.z, u1.w);
            dst[10] = pack2(m, 0.0f);             // channel 20 = mask, high half = pad
        }
    }
    // Each sample's slot is written only by its own quad (same wave):
    // draining our wave's ds_writes orders the cross-lane reads.
    asm volatile("s_waitcnt lgkmcnt(0)" ::: "memory");

    // ---- conv1: lane k computes output channels [5k, 5k+5), weights from LDS
    const int oc0 = lane4 * 5;
    float o[5][9];
#pragma unroll
    for (int c = 0; c < 5; ++c) {
        const float bb = b1[oc0 + c];
#pragma unroll
        for (int q = 0; q < 9; ++q) o[c][q] = bb;
    }

    // lo/hi halves processed SEQUENTIALLY through one fv[9] buffer: -9 live
    // VGPRs so the 128 budget holds.
#pragma unroll 1
    for (int icp = 0; icp < 10; ++icp) {          // ic pairs 0..19
        unsigned int fw[9];
#pragma unroll
        for (int q = 0; q < 9; ++q) fw[q] = fslot[q * 11 + icp];
        float fv[9];
#pragma unroll
        for (int q = 0; q < 9; ++q) fv[q] = bflo(fw[q]);
#pragma unroll
        for (int c = 0; c < 5; ++c)
            conv_acc(o[c], w1s + ((oc0 + c) * ICH + 2 * icp) * 9, fv);
#pragma unroll
        for (int q = 0; q < 9; ++q) fv[q] = bfhi(fw[q]);
#pragma unroll
        for (int c = 0; c < 5; ++c)
            conv_acc(o[c], w1s + ((oc0 + c) * ICH + 2 * icp + 1) * 9, fv);
    }
    {   // ic = 20 (mask channel)
        float f20[9];
#pragma unroll
        for (int q = 0; q < 9; ++q) f20[q] = bflo(fslot[q * 11 + 10]);
#pragma unroll
        for (int c = 0; c < 5; ++c)
            conv_acc(o[c], w1s + ((oc0 + c) * ICH + 20) * 9, f20);
    }

    // ---- lrelu + 2x2 maxpool (stride 1) on local 5 channels
    float pooled[5][4];
#pragma unroll
    for (int c = 0; c < 5; ++c) {
        float v[9];
#pragma unroll
        for (int q = 0; q < 9; ++q) v[q] = lrelu(o[c][q]);
        pooled[c][0] = fmaxf(fmaxf(v[0], v[1]), fmaxf(v[3], v[4]));
        pooled[c][1] = fmaxf(fmaxf(v[1], v[2]), fmaxf(v[4], v[5]));
        pooled[c][2] = fmaxf(fmaxf(v[3], v[4]), fmaxf(v[6], v[7]));
        pooled[c][3] = fmaxf(fmaxf(v[4], v[5]), fmaxf(v[7], v[8]));
    }

    // ---- conv2 (2x2 VALID): per-lane partial over its 5 oc, quad butterfly reduce.
    // FULLY unrolled: x30[j] writes must be statically indexed (rule #20).
    float x30[30];
#pragma unroll
    for (int j = 0; j < 30; ++j) {
        const float4* wr = (const float4*)(w2 + j * 80 + oc0 * 4);  // 16B aligned
        float acc = 0.0f;
#pragma unroll
        for (int c = 0; c < 5; ++c) {
            const float4 wv = wr[c];
            acc = fmaf(wv.x, pooled[c][0], acc);
            acc = fmaf(wv.y, pooled[c][1], acc);
            acc = fmaf(wv.z, pooled[c][2], acc);
            acc = fmaf(wv.w, pooled[c][3], acc);
        }
        acc += __shfl_xor(acc, 1, 64);
        acc += __shfl_xor(acc, 2, 64);
        x30[j] = lrelu(acc + b2[j]);
    }

    // ---- fc1 (38->120): lane k computes rows [30k, 30k+30)
    // FULLY unrolled: h1[jj] writes must be statically indexed (rule #20).
    float h1[30];
    const int j0 = lane4 * 30;
#pragma unroll
    for (int jj = 0; jj < 30; ++jj) {
        const float* wr = fw1 + (j0 + jj) * 38;
        float acc = fb1[j0 + jj] + wr[30 + ai];   // one-hot(act) contribution
        const float2* wp = (const float2*)wr;     // 8B aligned (38*4 = 152)
#pragma unroll
        for (int m = 0; m < 15; ++m) {
            const float2 wv = wp[m];
            acc = fmaf(wv.x, x30[2 * m],     acc);
            acc = fmaf(wv.y, x30[2 * m + 1], acc);
        }
        h1[jj] = lrelu(acc);
    }

    // ---- fc2 (120->84) + fc3 (84->1): per-lane partial dot over its 30 h1
    // with fc2 weights from LDS (quad-broadcast, conflict-free), butterfly
    // reduce per output, fold straight into fc3 (no h2 array).
    float z = fb3[0];
#pragma unroll 2
    for (int i = 0; i < 84; ++i) {
        const float2* wp = (const float2*)(fw2s + i * 120 + j0);  // 8B aligned
        float a = 0.0f;
#pragma unroll
        for (int m = 0; m < 15; ++m) {
            const float2 wv = wp[m];
            a = fmaf(wv.x, h1[2 * m],     a);
            a = fmaf(wv.y, h1[2 * m + 1], a);
        }
        a += __shfl_xor(a, 1, 64);
        a += __shfl_xor(a, 2, 64);
        z = fmaf(fw3[i], lrelu(a + fb2[i]), z);
    }

    if (lane4 == 0)
        out[sample] = 1.0f / (1.0f + __expf(-z));
}

extern "C" void kernel_launch(void* const* d_in, const int* in_sizes, int n_in,
                              void* d_out, int out_size, void* d_ws, size_t ws_size,
                              hipStream_t stream) {
    const int*   state = (const int*)d_in[0];
    const int*   des   = (const int*)d_in[1];
    const int*   act   = (const int*)d_in[2];
    const int*   asp   = (const int*)d_in[3];
    const int*   pmp   = (const int*)d_in[4];
    const float* pathf = (const float*)d_in[5];
    const float* linkf = (const float*)d_in[6];
    const float* w1    = (const float*)d_in[7];
    const float* b1    = (const float*)d_in[8];
    const float* w2    = (const float*)d_in[9];
    const float* b2    = (const float*)d_in[10];
    const float* fw1   = (const float*)d_in[11];
    const float* fb1   = (const float*)d_in[12];
    const float* fw2   = (const float*)d_in[13];
    const float* fb2   = (const float*)d_in[14];
    const float* fw3   = (const float*)d_in[15];
    const float* fb3   = (const float*)d_in[16];

    const int n = in_sizes[0];
    dim3 grid((n + SPB - 1) / SPB), block(TPB);
    hipLaunchKernelGGL(disc_kernel, grid, block, 0, stream,
                       state, des, act, asp, pmp, pathf, linkf,
                       w1, b1, w2, b2, fw1, fb1, fw2, fb2, fw3, fb3,
                       (float*)d_out, n);
}

// Round 8
// 512.249 us; speedup vs baseline: 2.0684x; 1.0699x over previous
//
#include <hip/hip_runtime.h>
#include <hip/hip_bf16.h>
#include <math.h>

// Problem constants
#define DDIM   300
#define PFN    12
#define LFN    8
#define ICH    21      // PF + LF + 1
#define TPB    256     // 4 waves/block; 4 lanes per sample
#define SPB    64      // samples per block
#define SLOT_DW 99     // per-sample feature slot: 9 positions * 11 dwords
#define W1N    3780    // 20*21*9  conv1 weights fp32 (15120 B)
#define W2N    2400    // 30*20*4  conv2 weights fp32 ( 9600 B)
#define FW1H   2280    // 120*38/2 fc1 weights bf16-packed dwords (9120 B)
#define FW2H   5040    // 84*120/2 fc2 weights bf16-packed dwords (20160 B)
#define BIASN  339     // b1(20)+b2(30)+fb1(120)+fb2(84)+fw3(84)+fb3(1)
// bias[] layout offsets:
#define OB1    0
#define OB2    20
#define OFB1   50
#define OFB2   170
#define OFW3   254
#define OFB3   338

__device__ __forceinline__ float lrelu(float v) { return v > 0.0f ? v : 0.2f * v; }

__device__ __forceinline__ unsigned int pack2(float a, float b) {
    union { __hip_bfloat162 h; unsigned int u; } cv;
    cv.h.x = __float2bfloat16(a);
    cv.h.y = __float2bfloat16(b);
    return cv.u;
}
__device__ __forceinline__ float bflo(unsigned int u) {
    union { unsigned int i; float f; } c; c.i = u << 16; return c.f;
}
__device__ __forceinline__ float bfhi(unsigned int u) {
    union { unsigned int i; float f; } c; c.i = u & 0xffff0000u; return c.f;
}

// 3x3 conv (pad=1) on a 3x3 grid: accumulate one input channel into 9 outputs.
__device__ __forceinline__ void conv_acc(float o[9], const float* __restrict__ w, const float fv[9]) {
#pragma unroll
    for (int t = 0; t < 9; ++t) {
        const int ky = t / 3 - 1, kx = t % 3 - 1;
        const float wv = w[t];
#pragma unroll
        for (int y = 0; y < 3; ++y) {
            const int iy = y + ky;
            if (iy < 0 || iy > 2) continue;
#pragma unroll
            for (int x = 0; x < 3; ++x) {
                const int ix = x + kx;
                if (ix < 0 || ix > 2) continue;
                o[y * 3 + x] = fmaf(wv, fv[iy * 3 + ix], o[y * 3 + x]);
            }
        }
    }
}

// r7 confirmed: VMEM->LDS for weights is the lever (372->230 us). This round
// finishes the migration: ALL weights+biases in LDS (fw1/fw2 as bf16 to fit),
// leaving only the feature gathers on the VMEM path (~25 instrs/wave).
// LDS total 80.7 KB -> still exactly 2 blocks/CU; W=2 keeps the 128-VGPR
// budget (toolchain model: budget = 256/W, W also caps resident waves/EU).
__launch_bounds__(TPB, 2)
__global__ void disc_kernel(
    const int* __restrict__ state, const int* __restrict__ des,
    const int* __restrict__ act,
    const int* __restrict__ asp_g,   // action_state_pad (S,9)
    const int* __restrict__ pmp_g,   // policy_mask_pad  (S,9)
    const float* __restrict__ path_feature,  // (S,D,12)
    const float* __restrict__ link_feature,  // (S,8)
    const float* __restrict__ w1, const float* __restrict__ b1,   // conv1 (20,21,3,3)
    const float* __restrict__ w2, const float* __restrict__ b2,   // conv2 (30,20,2,2)
    const float* __restrict__ fw1, const float* __restrict__ fb1, // (120,38)
    const float* __restrict__ fw2, const float* __restrict__ fb2, // (84,120)
    const float* __restrict__ fw3, const float* __restrict__ fb3, // (1,84)
    float* __restrict__ out, int n)
{
    __shared__ __align__(16) float w1s[W1N];          // 15120 B fp32
    __shared__ __align__(16) float w2s[W2N];          //  9600 B fp32
    __shared__ __align__(16) unsigned int fw1h[FW1H]; //  9120 B bf16x2
    __shared__ __align__(16) unsigned int fw2h[FW2H]; // 20160 B bf16x2
    __shared__ float bias[BIASN];                     //  1356 B fp32
    __shared__ unsigned int feat[SPB * SLOT_DW];      // 25344 B   => 80700 B total

    const int tid = threadIdx.x;

    // ---- Stage all weights/biases to LDS once per block.
    {
        const float4* s1 = (const float4*)w1;  float4* d1 = (float4*)w1s;
        for (int i = tid; i < W1N / 4; i += TPB) d1[i] = s1[i];
        const float4* s2 = (const float4*)w2;  float4* d2 = (float4*)w2s;
        for (int i = tid; i < W2N / 4; i += TPB) d2[i] = s2[i];
        const float2* sf1 = (const float2*)fw1;
        for (int i = tid; i < FW1H; i += TPB) { const float2 v = sf1[i]; fw1h[i] = pack2(v.x, v.y); }
        const float2* sf2 = (const float2*)fw2;
        for (int i = tid; i < FW2H; i += TPB) { const float2 v = sf2[i]; fw2h[i] = pack2(v.x, v.y); }
        for (int i = tid; i < BIASN; i += TPB) {
            float v;
            if      (i < OB2)  v = b1[i];
            else if (i < OFB1) v = b2[i - OB2];
            else if (i < OFB2) v = fb1[i - OFB1];
            else if (i < OFW3) v = fb2[i - OFB2];
            else if (i < OFB3) v = fw3[i - OFW3];
            else               v = fb3[0];
            bias[i] = v;
        }
    }
    __syncthreads();

    const int lane4  = tid & 3;       // lane within sample quad
    const int lsamp  = tid >> 2;      // sample within block
    const int sample = blockIdx.x * SPB + lsamp;
    if (sample >= n) return;

    const int s  = state[sample];
    const int d  = des[sample];
    const int ai = act[sample];

    const int* asp = asp_g + s * 9;
    const int* pmp = pmp_g + s * 9;
    unsigned int* fslot = feat + lsamp * SLOT_DW;

    // ---- Cooperative gather: lane k handles positions k, k+4, k+8.
    // NEW_INDEX packed as nibbles: p -> {7,0,1,6,8,2,5,4,3}
#pragma unroll
    for (int t = 0; t < 3; ++t) {
        const int p = lane4 + 4 * t;
        if (p < 9) {
            const int a  = (int)((0x345286107ULL >> (4 * p)) & 0xF);
            const int na = asp[a];
            const float m = (float)pmp[a];
            const float4* pf = (const float4*)(path_feature + (na * DDIM + d) * PFN);
            const float4 v0 = pf[0], v1 = pf[1], v2 = pf[2];
            const float4* lf = (const float4*)(link_feature + na * LFN);
            const float4 u0 = lf[0], u1 = lf[1];
            unsigned int* dst = fslot + p * 11;   // 22 bf16 per position (dword aligned)
            dst[0] = pack2(v0.x, v0.y); dst[1] = pack2(v0.z, v0.w);
            dst[2] = pack2(v1.x, v1.y); dst[3] = pack2(v1.z, v1.w);
            dst[4] = pack2(v2.x, v2.y); dst[5] = pack2(v2.z, v2.w);
            dst[6] = pack2(u0.x, u0.y); dst[7] = pack2(u0.z, u0.w);
            dst[8] = pack2(u1.x, u1.y); dst[9] = pack2(u1.z, u1.w);
            dst[10] = pack2(m, 0.0f);             // channel 20 = mask, high half = pad
        }
    }
    // Each sample's slot is written only by its own quad (same wave):
    // draining our wave's ds_writes orders the cross-lane reads.
    asm volatile("s_waitcnt lgkmcnt(0)" ::: "memory");

    // ---- conv1: lane k computes output channels [5k, 5k+5), weights from LDS
    const int oc0 = lane4 * 5;
    float o[5][9];
#pragma unroll
    for (int c = 0; c < 5; ++c) {
        const float bb = bias[OB1 + oc0 + c];
#pragma unroll
        for (int q = 0; q < 9; ++q) o[c][q] = bb;
    }

    // lo/hi halves processed SEQUENTIALLY through one fv[9] buffer: keeps
    // the live set under the 128-VGPR budget.
#pragma unroll 1
    for (int icp = 0; icp < 10; ++icp) {          // ic pairs 0..19
        unsigned int fw[9];
#pragma unroll
        for (int q = 0; q < 9; ++q) fw[q] = fslot[q * 11 + icp];
        float fv[9];
#pragma unroll
        for (int q = 0; q < 9; ++q) fv[q] = bflo(fw[q]);
#pragma unroll
        for (int c = 0; c < 5; ++c)
            conv_acc(o[c], w1s + ((oc0 + c) * ICH + 2 * icp) * 9, fv);
#pragma unroll
        for (int q = 0; q < 9; ++q) fv[q] = bfhi(fw[q]);
#pragma unroll
        for (int c = 0; c < 5; ++c)
            conv_acc(o[c], w1s + ((oc0 + c) * ICH + 2 * icp + 1) * 9, fv);
    }
    {   // ic = 20 (mask channel)
        float f20[9];
#pragma unroll
        for (int q = 0; q < 9; ++q) f20[q] = bflo(fslot[q * 11 + 10]);
#pragma unroll
        for (int c = 0; c < 5; ++c)
            conv_acc(o[c], w1s + ((oc0 + c) * ICH + 20) * 9, f20);
    }

    // ---- lrelu + 2x2 maxpool (stride 1) on local 5 channels
    float pooled[5][4];
#pragma unroll
    for (int c = 0; c < 5; ++c) {
        float v[9];
#pragma unroll
        for (int q = 0; q < 9; ++q) v[q] = lrelu(o[c][q]);
        pooled[c][0] = fmaxf(fmaxf(v[0], v[1]), fmaxf(v[3], v[4]));
        pooled[c][1] = fmaxf(fmaxf(v[1], v[2]), fmaxf(v[4], v[5]));
        pooled[c][2] = fmaxf(fmaxf(v[3], v[4]), fmaxf(v[6], v[7]));
        pooled[c][3] = fmaxf(fmaxf(v[4], v[5]), fmaxf(v[7], v[8]));
    }

    // ---- conv2 (2x2 VALID): per-lane partial over its 5 oc (weights from LDS),
    // quad butterfly reduce. FULLY unrolled (rule #20: x30 static writes).
    float x30[30];
#pragma unroll
    for (int j = 0; j < 30; ++j) {
        const float4* wr = (const float4*)(w2s + j * 80 + oc0 * 4);  // 16B aligned
        float acc = 0.0f;
#pragma unroll
        for (int c = 0; c < 5; ++c) {
            const float4 wv = wr[c];
            acc = fmaf(wv.x, pooled[c][0], acc);
            acc = fmaf(wv.y, pooled[c][1], acc);
            acc = fmaf(wv.z, pooled[c][2], acc);
            acc = fmaf(wv.w, pooled[c][3], acc);
        }
        acc += __shfl_xor(acc, 1, 64);
        acc += __shfl_xor(acc, 2, 64);
        x30[j] = lrelu(acc + bias[OB2 + j]);
    }

    // ---- fc1 (38->120): lane k computes rows [30k, 30k+30), bf16 weights
    // from LDS (row stride 19 dwords). FULLY unrolled (rule #20: h1 static).
    float h1[30];
    const int j0 = lane4 * 30;
    const int ohd  = (30 + ai) >> 1;   // one-hot dword within row
    const int ohodd = (30 + ai) & 1;   // which bf16 half
#pragma unroll
    for (int jj = 0; jj < 30; ++jj) {
        const unsigned int* wr = fw1h + (j0 + jj) * 19;
        const unsigned int uoh = wr[ohd];
        float acc = bias[OFB1 + j0 + jj] + (ohodd ? bfhi(uoh) : bflo(uoh));
#pragma unroll
        for (int m = 0; m < 15; ++m) {
            const unsigned int u = wr[m];
            acc = fmaf(bflo(u), x30[2 * m],     acc);
            acc = fmaf(bfhi(u), x30[2 * m + 1], acc);
        }
        h1[jj] = lrelu(acc);
    }

    // ---- fc2 (120->84) + fc3 (84->1): per-lane partial dot over its 30 h1
    // with bf16 fc2 weights from LDS (row stride 60 dw, lane offset 15 dw,
    // conflict-free banks), butterfly reduce, fold straight into fc3.
    float z = bias[OFB3];
#pragma unroll 2
    for (int i = 0; i < 84; ++i) {
        const unsigned int* wp = fw2h + i * 60 + lane4 * 15;
        float a = 0.0f;
#pragma unroll
        for (int m = 0; m < 15; ++m) {
            const unsigned int u = wp[m];
            a = fmaf(bflo(u), h1[2 * m],     a);
            a = fmaf(bfhi(u), h1[2 * m + 1], a);
        }
        a += __shfl_xor(a, 1, 64);
        a += __shfl_xor(a, 2, 64);
        z = fmaf(bias[OFW3 + i], lrelu(a + bias[OFB2 + i]), z);
    }

    if (lane4 == 0)
        out[sample] = 1.0f / (1.0f + __expf(-z));
}

extern "C" void kernel_launch(void* const* d_in, const int* in_sizes, int n_in,
                              void* d_out, int out_size, void* d_ws, size_t ws_size,
                              hipStream_t stream) {
    const int*   state = (const int*)d_in[0];
    const int*   des   = (const int*)d_in[1];
    const int*   act   = (const int*)d_in[2];
    const int*   asp   = (const int*)d_in[3];
    const int*   pmp   = (const int*)d_in[4];
    const float* pathf = (const float*)d_in[5];
    const float* linkf = (const float*)d_in[6];
    const float* w1    = (const float*)d_in[7];
    const float* b1    = (const float*)d_in[8];
    const float* w2    = (const float*)d_in[9];
    const float* b2    = (const float*)d_in[10];
    const float* fw1   = (const float*)d_in[11];
    const float* fb1   = (const float*)d_in[12];
    const float* fw2   = (const float*)d_in[13];
    const float* fb2   = (const float*)d_in[14];
    const float* fw3   = (const float*)d_in[15];
    const float* fb3   = (const float*)d_in[16];

    const int n = in_sizes[0];
    dim3 grid((n + SPB - 1) / SPB), block(TPB);
    hipLaunchKernelGGL(disc_kernel, grid, block, 0, stream,
                       state, des, act, asp, pmp, pathf, linkf,
                       w1, b1, w2, b2, fw1, fb1, fw2, fb2, fw3, fb3,
                       (float*)d_out, n);
}

// Round 9
// 459.883 us; speedup vs baseline: 2.3039x; 1.1139x over previous
//
#include <hip/hip_runtime.h>
#include <hip/hip_bf16.h>
#include <math.h>

// Problem constants
#define DDIM   300
#define PFN    12
#define LFN    8
#define ICH    21      // PF + LF + 1
#define TPB    256     // 4 waves/block; 4 lanes per sample
#define SPB    64      // samples per block
#define SLOT_DW 99     // per-sample feature slot: 9 positions * 11 dwords
#define W1P    1980    // 20 oc * 11 icp * 9 taps  bf16-pair dwords (7920 B)
#define W2N    2400    // 30*20*4  conv2 weights fp32 ( 9600 B)
#define FW1H   2280    // 120*38/2 fc1 weights bf16-packed dwords (9120 B)
#define FW2H   5040    // 84*120/2 fc2 weights bf16-packed dwords (20160 B)
#define BIASN  339     // b1(20)+b2(30)+fb1(120)+fb2(84)+fw3(84)+fb3(1)
// bias[] layout offsets:
#define OB1    0
#define OB2    20
#define OFB1   50
#define OFB2   170
#define OFW3   254
#define OFB3   338

__device__ __forceinline__ float lrelu(float v) { return v > 0.0f ? v : 0.2f * v; }

__device__ __forceinline__ unsigned int pack2(float a, float b) {
    union { __hip_bfloat162 h; unsigned int u; } cv;
    cv.h.x = __float2bfloat16(a);
    cv.h.y = __float2bfloat16(b);
    return cv.u;
}
__device__ __forceinline__ float bflo(unsigned int u) {
    union { unsigned int i; float f; } c; c.i = u << 16; return c.f;
}
__device__ __forceinline__ float bfhi(unsigned int u) {
    union { unsigned int i; float f; } c; c.i = u & 0xffff0000u; return c.f;
}

// Packed bf16 dot-2 with f32 accumulate: d = a.lo*b.lo + a.hi*b.hi + c.
// One VALU issue for 2 MACs and ZERO unpack ops (VOP3P, CDNA3/4).
__device__ __forceinline__ float dot2bf(unsigned int a, unsigned int b, float c) {
    float d;
    asm("v_dot2_f32_bf16 %0, %1, %2, %3" : "=v"(d) : "v"(a), "v"(b), "v"(c));
    return d;
}

// 3x3 conv (pad=1) on a 3x3 grid: accumulate one packed ic-PAIR into 9 outputs
// via dot2 (weights and features both bf16-pair dwords).
__device__ __forceinline__ void conv_acc2(float o[9], const unsigned int* __restrict__ w,
                                          const unsigned int fv[9]) {
#pragma unroll
    for (int t = 0; t < 9; ++t) {
        const int ky = t / 3 - 1, kx = t % 3 - 1;
        const unsigned int wv = w[t];
#pragma unroll
        for (int y = 0; y < 3; ++y) {
            const int iy = y + ky;
            if (iy < 0 || iy > 2) continue;
#pragma unroll
            for (int x = 0; x < 3; ++x) {
                const int ix = x + kx;
                if (ix < 0 || ix > 2) continue;
                o[y * 3 + x] = dot2bf(wv, fv[iy * 3 + ix], o[y * 3 + x]);
            }
        }
    }
}

// r8: all-weights-in-LDS got 230->190us, VALUBusy 60%. Occupancy is walled at
// 2 waves/EU (LDS 2 blocks/CU; W=2 budget 128 VGPR). Remaining lever = VALU
// instruction count: ~3600 bf16-unpack + scalar fma. This round: everything
// bf16-paired runs through v_dot2_f32_bf16 (1 issue = 2 MACs, no unpacks);
// per-lane VALU ~12.8k -> ~5.5k. conv2 stays f32 (unpacked operands).
__launch_bounds__(TPB, 2)
__global__ void disc_kernel(
    const int* __restrict__ state, const int* __restrict__ des,
    const int* __restrict__ act,
    const int* __restrict__ asp_g,   // action_state_pad (S,9)
    const int* __restrict__ pmp_g,   // policy_mask_pad  (S,9)
    const float* __restrict__ path_feature,  // (S,D,12)
    const float* __restrict__ link_feature,  // (S,8)
    const float* __restrict__ w1, const float* __restrict__ b1,   // conv1 (20,21,3,3)
    const float* __restrict__ w2, const float* __restrict__ b2,   // conv2 (30,20,2,2)
    const float* __restrict__ fw1, const float* __restrict__ fb1, // (120,38)
    const float* __restrict__ fw2, const float* __restrict__ fb2, // (84,120)
    const float* __restrict__ fw3, const float* __restrict__ fb3, // (1,84)
    float* __restrict__ out, int n)
{
    __shared__ __align__(16) unsigned int w1p[W1P];   //  7920 B bf16 ic-pairs
    __shared__ __align__(16) float w2s[W2N];          //  9600 B fp32
    __shared__ __align__(16) unsigned int fw1h[FW1H]; //  9120 B bf16x2
    __shared__ __align__(16) unsigned int fw2h[FW2H]; // 20160 B bf16x2
    __shared__ float bias[BIASN];                     //  1356 B fp32
    __shared__ unsigned int feat[SPB * SLOT_DW];      // 25344 B  => 73500 B total

    const int tid = threadIdx.x;

    // ---- Stage all weights/biases to LDS once per block.
    {
        // conv1 weights as bf16 ic-pair dwords: w1p[oc][icp][t] =
        // pack2(w1[oc][2icp][t], w1[oc][2icp+1][t]); icp==10 pairs ic20 with 0.
        for (int i = tid; i < W1P; i += TPB) {
            const int oc = i / 99, r = i % 99, icp = r / 9, t = r % 9;
            const float lo = w1[(oc * ICH + 2 * icp) * 9 + t];
            const float hi = (icp < 10) ? w1[(oc * ICH + 2 * icp + 1) * 9 + t] : 0.0f;
            w1p[i] = pack2(lo, hi);
        }
        const float4* s2 = (const float4*)w2;  float4* d2 = (float4*)w2s;
        for (int i = tid; i < W2N / 4; i += TPB) d2[i] = s2[i];
        const float2* sf1 = (const float2*)fw1;
        for (int i = tid; i < FW1H; i += TPB) { const float2 v = sf1[i]; fw1h[i] = pack2(v.x, v.y); }
        const float2* sf2 = (const float2*)fw2;
        for (int i = tid; i < FW2H; i += TPB) { const float2 v = sf2[i]; fw2h[i] = pack2(v.x, v.y); }
        for (int i = tid; i < BIASN; i += TPB) {
            float v;
            if      (i < OB2)  v = b1[i];
            else if (i < OFB1) v = b2[i - OB2];
            else if (i < OFB2) v = fb1[i - OFB1];
            else if (i < OFW3) v = fb2[i - OFB2];
            else if (i < OFB3) v = fw3[i - OFW3];
            else               v = fb3[0];
            bias[i] = v;
        }
    }
    __syncthreads();

    const int lane4  = tid & 3;       // lane within sample quad
    const int lsamp  = tid >> 2;      // sample within block
    const int sample = blockIdx.x * SPB + lsamp;
    if (sample >= n) return;

    const int s  = state[sample];
    const int d  = des[sample];
    const int ai = act[sample];

    const int* asp = asp_g + s * 9;
    const int* pmp = pmp_g + s * 9;
    unsigned int* fslot = feat + lsamp * SLOT_DW;

    // ---- Cooperative gather: lane k handles positions k, k+4, k+8.
    // NEW_INDEX packed as nibbles: p -> {7,0,1,6,8,2,5,4,3}
#pragma unroll
    for (int t = 0; t < 3; ++t) {
        const int p = lane4 + 4 * t;
        if (p < 9) {
            const int a  = (int)((0x345286107ULL >> (4 * p)) & 0xF);
            const int na = asp[a];
            const float m = (float)pmp[a];
            const float4* pf = (const float4*)(path_feature + (na * DDIM + d) * PFN);
            const float4 v0 = pf[0], v1 = pf[1], v2 = pf[2];
            const float4* lf = (const float4*)(link_feature + na * LFN);
            const float4 u0 = lf[0], u1 = lf[1];
            unsigned int* dst = fslot + p * 11;   // 22 bf16 per position (dword aligned)
            dst[0] = pack2(v0.x, v0.y); dst[1] = pack2(v0.z, v0.w);
            dst[2] = pack2(v1.x, v1.y); dst[3] = pack2(v1.z, v1.w);
            dst[4] = pack2(v2.x, v2.y); dst[5] = pack2(v2.z, v2.w);
            dst[6] = pack2(u0.x, u0.y); dst[7] = pack2(u0.z, u0.w);
            dst[8] = pack2(u1.x, u1.y); dst[9] = pack2(u1.z, u1.w);
            dst[10] = pack2(m, 0.0f);             // channel 20 = mask, high half = pad
        }
    }
    // Each sample's slot is written only by its own quad (same wave):
    // draining our wave's ds_writes orders the cross-lane reads.
    asm volatile("s_waitcnt lgkmcnt(0)" ::: "memory");

    // ---- conv1: lane k computes output channels [5k, 5k+5) via dot2 over
    // ic-pairs; 11 packed dwords cover all 21 channels (incl. mask, hi=0).
    const int oc0 = lane4 * 5;
    float o[5][9];
#pragma unroll
    for (int c = 0; c < 5; ++c) {
        const float bb = bias[OB1 + oc0 + c];
#pragma unroll
        for (int q = 0; q < 9; ++q) o[c][q] = bb;
    }

#pragma unroll 1
    for (int icp = 0; icp < 11; ++icp) {
        unsigned int fwd[9];
#pragma unroll
        for (int q = 0; q < 9; ++q) fwd[q] = fslot[q * 11 + icp];
        unsigned int wt[9];
#pragma unroll
        for (int c = 0; c < 5; ++c) {
            const unsigned int* wrow = w1p + (oc0 + c) * 99 + icp * 9;
#pragma unroll
            for (int t = 0; t < 9; ++t) wt[t] = wrow[t];
            conv_acc2(o[c], wt, fwd);
        }
    }

    // ---- lrelu + 2x2 maxpool (stride 1) on local 5 channels
    float pooled[5][4];
#pragma unroll
    for (int c = 0; c < 5; ++c) {
        float v[9];
#pragma unroll
        for (int q = 0; q < 9; ++q) v[q] = lrelu(o[c][q]);
        pooled[c][0] = fmaxf(fmaxf(v[0], v[1]), fmaxf(v[3], v[4]));
        pooled[c][1] = fmaxf(fmaxf(v[1], v[2]), fmaxf(v[4], v[5]));
        pooled[c][2] = fmaxf(fmaxf(v[3], v[4]), fmaxf(v[6], v[7]));
        pooled[c][3] = fmaxf(fmaxf(v[4], v[5]), fmaxf(v[7], v[8]));
    }

    // ---- conv2 (2x2 VALID): per-lane partial over its 5 oc (f32 weights from
    // LDS), quad butterfly reduce. FULLY unrolled (rule #20: static writes).
    float x30[30];
#pragma unroll
    for (int j = 0; j < 30; ++j) {
        const float4* wr = (const float4*)(w2s + j * 80 + oc0 * 4);  // 16B aligned
        float acc = 0.0f;
#pragma unroll
        for (int c = 0; c < 5; ++c) {
            const float4 wv = wr[c];
            acc = fmaf(wv.x, pooled[c][0], acc);
            acc = fmaf(wv.y, pooled[c][1], acc);
            acc = fmaf(wv.z, pooled[c][2], acc);
            acc = fmaf(wv.w, pooled[c][3], acc);
        }
        acc += __shfl_xor(acc, 1, 64);
        acc += __shfl_xor(acc, 2, 64);
        x30[j] = lrelu(acc + bias[OB2 + j]);
    }

    // Pack x30 once to bf16 pairs for the dot2 FC path (15 cvt_pk).
    unsigned int xp[15];
#pragma unroll
    for (int m = 0; m < 15; ++m) xp[m] = pack2(x30[2 * m], x30[2 * m + 1]);

    // ---- fc1 (38->120): lane k computes rows [30k, 30k+30) via dot2.
    float h1[30];
    const int j0 = lane4 * 30;
    const int ohd   = (30 + ai) >> 1;  // one-hot dword within 19-dw row
    const int ohodd = (30 + ai) & 1;   // which bf16 half
#pragma unroll
    for (int jj = 0; jj < 30; ++jj) {
        const unsigned int* wr = fw1h + (j0 + jj) * 19;
        const unsigned int uoh = wr[ohd];
        float acc = bias[OFB1 + j0 + jj] + (ohodd ? bfhi(uoh) : bflo(uoh));
#pragma unroll
        for (int m = 0; m < 15; ++m)
            acc = dot2bf(wr[m], xp[m], acc);
        h1[jj] = lrelu(acc);
    }

    // Pack h1 once to bf16 pairs (15 cvt_pk).
    unsigned int hp[15];
#pragma unroll
    for (int m = 0; m < 15; ++m) hp[m] = pack2(h1[2 * m], h1[2 * m + 1]);

    // ---- fc2 (120->84) + fc3 (84->1): per-lane dot2 partial over its 30 h1,
    // butterfly reduce, fold straight into fc3 (no h2 array).
    float z = bias[OFB3];
#pragma unroll 2
    for (int i = 0; i < 84; ++i) {
        const unsigned int* wp = fw2h + i * 60 + lane4 * 15;
        float a = 0.0f;
#pragma unroll
        for (int m = 0; m < 15; ++m)
            a = dot2bf(wp[m], hp[m], a);
        a += __shfl_xor(a, 1, 64);
        a += __shfl_xor(a, 2, 64);
        z = fmaf(bias[OFW3 + i], lrelu(a + bias[OFB2 + i]), z);
    }

    if (lane4 == 0)
        out[sample] = 1.0f / (1.0f + __expf(-z));
}

extern "C" void kernel_launch(void* const* d_in, const int* in_sizes, int n_in,
                              void* d_out, int out_size, void* d_ws, size_t ws_size,
                              hipStream_t stream) {
    const int*   state = (const int*)d_in[0];
    const int*   des   = (const int*)d_in[1];
    const int*   act   = (const int*)d_in[2];
    const int*   asp   = (const int*)d_in[3];
    const int*   pmp   = (const int*)d_in[4];
    const float* pathf = (const float*)d_in[5];
    const float* linkf = (const float*)d_in[6];
    const float* w1    = (const float*)d_in[7];
    const float* b1    = (const float*)d_in[8];
    const float* w2    = (const float*)d_in[9];
    const float* b2    = (const float*)d_in[10];
    const float* fw1   = (const float*)d_in[11];
    const float* fb1   = (const float*)d_in[12];
    const float* fw2   = (const float*)d_in[13];
    const float* fb2   = (const float*)d_in[14];
    const float* fw3   = (const float*)d_in[15];
    const float* fb3   = (const float*)d_in[16];

    const int n = in_sizes[0];
    dim3 grid((n + SPB - 1) / SPB), block(TPB);
    hipLaunchKernelGGL(disc_kernel, grid, block, 0, stream,
                       state, des, act, asp, pmp, pathf, linkf,
                       w1, b1, w2, b2, fw1, fb1, fw2, fb2, fw3, fb3,
                       (float*)d_out, n);
}